// Round 2
// baseline (309.969 us; speedup 1.0000x reference)
//
#include <hip/hip_runtime.h>

#define FUZZ 2187
#define NFEAT 7
#define MID 512
#define NCLS 10
#define BATCH 4096
#define SSTR 2192   // padded row stride for S/G (21 rows each)
#define NCHUNK 81   // k-chunks of 27 consecutive k
#define PROWS 13    // per-chunk partial rows: 4 (j=0..3 block-uniform digit) + 9 (j=4..6 by m)

// ---------------------------------------------------------------------------
// Kernel 1: partial reduction of wei (15309 x 2187 row-major), no atomics.
// k = 27*by + kk. Digits d[0..3] are block-uniform; d[4..6] are compile-time
// functions of kk (kk/9, (kk/3)%3, kk%3). Per element: exactly one v_add.
// Writes Spart[by][0..3][n]  = sum_kk wei[(k*7+j)*FUZZ+n]        (j=0..3)
//        Spart[by][4+r][n]   = sum over kk hitting (j,m), r=(j-4)*3+m
// ---------------------------------------------------------------------------
__global__ __launch_bounds__(256) void k_reduce_wei(const float* __restrict__ wei,
                                                    float* __restrict__ Spart) {
    int n = blockIdx.x * 256 + threadIdx.x;
    if (n >= FUZZ) return;
    int by = blockIdx.y;

    float sum4[4];
    float acc9[9];
#pragma unroll
    for (int j = 0; j < 4; ++j) sum4[j] = 0.f;
#pragma unroll
    for (int r = 0; r < 9; ++r) acc9[r] = 0.f;

    const float* base = wei + (size_t)(by * 27) * 7 * FUZZ + n;
#pragma unroll
    for (int kk = 0; kk < 27; ++kk) {
        const float* rp = base + (size_t)kk * 7 * FUZZ;
        float v0 = rp[0];
        float v1 = rp[(size_t)1 * FUZZ];
        float v2 = rp[(size_t)2 * FUZZ];
        float v3 = rp[(size_t)3 * FUZZ];
        float v4 = rp[(size_t)4 * FUZZ];
        float v5 = rp[(size_t)5 * FUZZ];
        float v6 = rp[(size_t)6 * FUZZ];
        sum4[0] += v0;
        sum4[1] += v1;
        sum4[2] += v2;
        sum4[3] += v3;
        acc9[0 + (kk / 9)]       += v4;   // d[4] = kk/9     (compile-time)
        acc9[3 + ((kk / 3) % 3)] += v5;   // d[5] = (kk/3)%3 (compile-time)
        acc9[6 + (kk % 3)]       += v6;   // d[6] = kk%3     (compile-time)
    }

    float* outp = Spart + (size_t)by * PROWS * FUZZ + n;
#pragma unroll
    for (int j = 0; j < 4; ++j) outp[(size_t)j * FUZZ] = sum4[j];
#pragma unroll
    for (int r = 0; r < 9; ++r) outp[(size_t)(4 + r) * FUZZ] = acc9[r];
}

// ---------------------------------------------------------------------------
// Kernel 2: recombine partials into S[21][SSTR].
// t<12:  j=t/3, m=t%3 -> sum Spart[by][j][n] over the 27 by with digit_j(by)==m
// t>=12: r=t-8 (rows 4..12) -> sum Spart[by][r][n] over all 81 by
// Grid (9 n-tiles, 21 t).
// ---------------------------------------------------------------------------
__global__ __launch_bounds__(256) void k_reduce2(const float* __restrict__ Spart,
                                                 float* __restrict__ S) {
    int n = blockIdx.x * 256 + threadIdx.x;
    if (n >= FUZZ) return;
    int t = blockIdx.y;
    float s;
    if (t < 12) {
        int j = t / 3, m = t % 3;
        const int places[4] = {27, 9, 3, 1};
        int ops[3];
        int o = 0;
#pragma unroll
        for (int q = 0; q < 4; ++q)
            if (q != j) ops[o++] = places[q];
        int byb = m * places[j];
        float s0 = 0.f, s1 = 0.f, s2 = 0.f;
#pragma unroll 9
        for (int c = 0; c < 27; c += 3) {
            int by0 = byb + (c / 9) * ops[0] + (((c + 0) / 3) % 3) * ops[1] + ((c + 0) % 3) * ops[2];
            int by1 = byb + (c / 9) * ops[0] + (((c + 1) / 3) % 3) * ops[1] + ((c + 1) % 3) * ops[2];
            int by2 = byb + (c / 9) * ops[0] + (((c + 2) / 3) % 3) * ops[1] + ((c + 2) % 3) * ops[2];
            s0 += Spart[((size_t)by0 * PROWS + j) * FUZZ + n];
            s1 += Spart[((size_t)by1 * PROWS + j) * FUZZ + n];
            s2 += Spart[((size_t)by2 * PROWS + j) * FUZZ + n];
        }
        s = s0 + s1 + s2;
    } else {
        int row = t - 8;   // 4..12
        float s0 = 0.f, s1 = 0.f, s2 = 0.f;
        for (int by = 0; by < 81; by += 3) {
            s0 += Spart[((size_t)(by + 0) * PROWS + row) * FUZZ + n];
            s1 += Spart[((size_t)(by + 1) * PROWS + row) * FUZZ + n];
            s2 += Spart[((size_t)(by + 2) * PROWS + row) * FUZZ + n];
        }
        s = s0 + s1 + s2;
    }
    S[t * SSTR + n] = s;
}

__device__ __forceinline__ float wave_sum(float v) {
#pragma unroll
    for (int off = 32; off > 0; off >>= 1) v += __shfl_down(v, off, 64);
    return v;
}

// ---------------------------------------------------------------------------
// Kernel 3: SW1[t][i] = sum_n S[t,n]*W1[i,n];  ws1[i] = sum_n W1[i,n]
// One 256-thread block per i (4 waves split the n-range, LDS combine).
// ---------------------------------------------------------------------------
__global__ __launch_bounds__(256) void k_sw1(const float* __restrict__ S,
                                             const float* __restrict__ W1,
                                             float* __restrict__ SW1,
                                             float* __restrict__ ws1) {
    int i = blockIdx.x;
    int tid = threadIdx.x;
    float acc[21];
    float aw = 0.f;
#pragma unroll
    for (int t = 0; t < 21; ++t) acc[t] = 0.f;
    for (int n = tid; n < FUZZ; n += 256) {
        float w1 = W1[(size_t)i * FUZZ + n];
        aw += w1;
#pragma unroll
        for (int t = 0; t < 21; ++t) acc[t] += S[t * SSTR + n] * w1;
    }
#pragma unroll
    for (int t = 0; t < 21; ++t) acc[t] = wave_sum(acc[t]);
    aw = wave_sum(aw);
    __shared__ float red[4][22];
    int w = tid >> 6, lane = tid & 63;
    if (lane == 0) {
#pragma unroll
        for (int t = 0; t < 21; ++t) red[w][t] = acc[t];
        red[w][21] = aw;
    }
    __syncthreads();
    if (tid < 22) {
        float v = red[0][tid] + red[1][tid] + red[2][tid] + red[3][tid];
        if (tid < 21) SW1[tid * MID + i] = v;
        else          ws1[i] = v;
    }
}

// ---------------------------------------------------------------------------
// Kernel 4: G[t][n] = sum_i SW1[t,i]*W2[n,i];  q[n] = sum_i ws1[i]*W2[n,i];
//           p[n] = sum_i b1[i]*W2[n,i].  One wave per n (2187 blocks).
// ---------------------------------------------------------------------------
__global__ __launch_bounds__(64) void k_g(const float* __restrict__ SW1,
                                          const float* __restrict__ ws1,
                                          const float* __restrict__ b1,
                                          const float* __restrict__ W2,
                                          float* __restrict__ G,
                                          float* __restrict__ q,
                                          float* __restrict__ p) {
    int n = blockIdx.x;
    int lane = threadIdx.x;
    float acc[21];
    float aq = 0.f, ap = 0.f;
#pragma unroll
    for (int t = 0; t < 21; ++t) acc[t] = 0.f;
    for (int i = lane; i < MID; i += 64) {
        float w2 = W2[(size_t)n * MID + i];
        aq += ws1[i] * w2;
        ap += b1[i] * w2;
#pragma unroll
        for (int t = 0; t < 21; ++t) acc[t] += SW1[t * MID + i] * w2;
    }
#pragma unroll
    for (int t = 0; t < 21; ++t) acc[t] = wave_sum(acc[t]);
    aq = wave_sum(aq);
    ap = wave_sum(ap);
    if (lane == 0) {
#pragma unroll
        for (int t = 0; t < 21; ++t) G[t * SSTR + n] = acc[t];
        q[n] = aq;
        p[n] = ap;
    }
}

// ---------------------------------------------------------------------------
// Kernel 5: H[t][c] = sum_n (S+G)[t,n]*W3[c,n]
//           v[c] = sum_n (1+q[n])*W3[c,n]
//           w[c] = sum_n (p[n]+b2[n])*W3[c,n] + b3[c]
//           T[t] = sum_n S[t,n]                      (block 10)
// 512-thread blocks (8 waves, LDS combine), grid 11.
// ---------------------------------------------------------------------------
__global__ __launch_bounds__(512) void k_h(const float* __restrict__ S,
                                           const float* __restrict__ G,
                                           const float* __restrict__ q,
                                           const float* __restrict__ p,
                                           const float* __restrict__ b2,
                                           const float* __restrict__ b3,
                                           const float* __restrict__ W3,
                                           float* __restrict__ H,
                                           float* __restrict__ v,
                                           float* __restrict__ w,
                                           float* __restrict__ T) {
    int c = blockIdx.x;
    int tid = threadIdx.x;
    int wv = tid >> 6, lane = tid & 63;
    __shared__ float red[8][24];
    float acc[21];
#pragma unroll
    for (int t = 0; t < 21; ++t) acc[t] = 0.f;
    if (c < NCLS) {
        float av = 0.f, aw = 0.f;
        for (int n = tid; n < FUZZ; n += 512) {
            float w3 = W3[(size_t)c * FUZZ + n];
            av += (1.0f + q[n]) * w3;
            aw += (p[n] + b2[n]) * w3;
#pragma unroll
            for (int t = 0; t < 21; ++t)
                acc[t] += (S[t * SSTR + n] + G[t * SSTR + n]) * w3;
        }
#pragma unroll
        for (int t = 0; t < 21; ++t) acc[t] = wave_sum(acc[t]);
        av = wave_sum(av);
        aw = wave_sum(aw);
        if (lane == 0) {
#pragma unroll
            for (int t = 0; t < 21; ++t) red[wv][t] = acc[t];
            red[wv][21] = av;
            red[wv][22] = aw;
        }
        __syncthreads();
        if (tid < 23) {
            float s = 0.f;
#pragma unroll
            for (int k = 0; k < 8; ++k) s += red[k][tid];
            if (tid < 21)      H[tid * NCLS + c] = s;
            else if (tid == 21) v[c] = s;
            else               w[c] = s + b3[c];
        }
    } else {
        for (int n = tid; n < FUZZ; n += 512) {
#pragma unroll
            for (int t = 0; t < 21; ++t) acc[t] += S[t * SSTR + n];
        }
#pragma unroll
        for (int t = 0; t < 21; ++t) acc[t] = wave_sum(acc[t]);
        if (lane == 0) {
#pragma unroll
            for (int t = 0; t < 21; ++t) red[wv][t] = acc[t];
        }
        __syncthreads();
        if (tid < 21) {
            float s = 0.f;
#pragma unroll
            for (int k = 0; k < 8; ++k) s += red[k][tid];
            T[tid] = s;
        }
    }
}

// ---------------------------------------------------------------------------
// Kernel 6: per-batch epilogue.
// u[j,m] = exp(-(x[b,j]-c[j,m])^2 / b[j,m]^2)
// r = 2187*bais + sum u*T
// out[b,c] = leaky_relu( (sum u*H[:,c] + bais*v[c]) / r + w[c], 0.2 )
// ---------------------------------------------------------------------------
__global__ __launch_bounds__(256) void k_out(const float* __restrict__ x,
                                             const float* __restrict__ cc,
                                             const float* __restrict__ bbv,
                                             const float* __restrict__ bais,
                                             const float* __restrict__ T,
                                             const float* __restrict__ H,
                                             const float* __restrict__ v,
                                             const float* __restrict__ w,
                                             float* __restrict__ out) {
    int b = blockIdx.x * 256 + threadIdx.x;
    if (b >= BATCH) return;
    float xv[NFEAT];
#pragma unroll
    for (int j = 0; j < NFEAT; ++j) xv[j] = x[b * NFEAT + j];
    float u[21];
#pragma unroll
    for (int j = 0; j < NFEAT; ++j) {
#pragma unroll
        for (int m = 0; m < 3; ++m) {
            float d = xv[j] - cc[j * 3 + m];
            float bv = bbv[j * 3 + m];
            u[j * 3 + m] = expf(-(d * d) / (bv * bv));
        }
    }
    float ba = bais[0];
    float r = 2187.0f * ba;
#pragma unroll
    for (int t = 0; t < 21; ++t) r += u[t] * T[t];
    float inv = 1.0f / r;
#pragma unroll
    for (int c = 0; c < NCLS; ++c) {
        float s = 0.f;
#pragma unroll
        for (int t = 0; t < 21; ++t) s += u[t] * H[t * NCLS + c];
        float h = (s + ba * v[c]) * inv + w[c];
        out[b * NCLS + c] = (h >= 0.f) ? h : 0.2f * h;
    }
}

extern "C" void kernel_launch(void* const* d_in, const int* in_sizes, int n_in,
                              void* d_out, int out_size, void* d_ws, size_t ws_size,
                              hipStream_t stream) {
    const float* x    = (const float*)d_in[0];
    const float* c    = (const float*)d_in[1];
    const float* bbv  = (const float*)d_in[2];
    const float* wei  = (const float*)d_in[3];
    const float* bais = (const float*)d_in[4];
    const float* W1   = (const float*)d_in[5];
    const float* b1   = (const float*)d_in[6];
    const float* W2   = (const float*)d_in[7];
    const float* b2   = (const float*)d_in[8];
    const float* W3   = (const float*)d_in[9];
    const float* b3   = (const float*)d_in[10];

    float* ws    = (float*)d_ws;
    float* Spart = ws;                                   // 81*13*2187 = 2302911
    float* S     = Spart + 2302912;                      // 21*SSTR
    float* G     = S + 21 * SSTR;                        // 21*SSTR
    float* SW1   = G + 21 * SSTR;                        // 21*512
    float* ws1   = SW1 + 21 * MID;                       // 512
    float* q     = ws1 + MID;                            // SSTR
    float* p     = q + SSTR;                             // SSTR
    float* T     = p + SSTR;                             // 32
    float* H     = T + 32;                               // 224 (21*10 used)
    float* v     = H + 224;                              // 16
    float* w     = v + 16;                               // 16

    k_reduce_wei<<<dim3(9, NCHUNK), 256, 0, stream>>>(wei, Spart);
    k_reduce2<<<dim3(9, 21), 256, 0, stream>>>(Spart, S);
    k_sw1<<<MID, 256, 0, stream>>>(S, W1, SW1, ws1);
    k_g<<<FUZZ, 64, 0, stream>>>(SW1, ws1, b1, W2, G, q, p);
    k_h<<<NCLS + 1, 512, 0, stream>>>(S, G, q, p, b2, b3, W3, H, v, w, T);
    k_out<<<(BATCH + 255) / 256, 256, 0, stream>>>(x, c, bbv, bais, T, H, v, w,
                                                   (float*)d_out);
}

// Round 3
// 305.075 us; speedup vs baseline: 1.0160x; 1.0160x over previous
//
#include <hip/hip_runtime.h>

#define FUZZ 2187
#define NFEAT 7
#define MID 512
#define NCLS 10
#define BATCH 4096
#define SSTR 2192   // padded row stride for S/G (21 rows each), mult of 4
#define NCH 243     // k-chunks of 9 consecutive k
#define PROWS 11    // 5 uniform-digit rows (j=0..4) + 3 (j=5 by m) + 3 (j=6 by m)
#define PSTR 2188   // padded Spart row stride (mult of 4 -> 16B-aligned float4)
#define NF4 546     // full float4 columns; col 546 covers the 3-float tail

__device__ __forceinline__ void f4add(float4& a, const float4& b) {
    a.x += b.x; a.y += b.y; a.z += b.z; a.w += b.w;
}

// ---------------------------------------------------------------------------
// Kernel 1: partial reduction of wei (15309 x 2187 row-major), no atomics.
// k = 9*by + kk. Digits d[0..4] are block-uniform; d[5]=kk/3, d[6]=kk%3 are
// compile-time under unroll. float4 loads (dwordx4, dword-aligned is enough).
// Spart[by][0..4][n]  = sum_kk wei[(k*7+j)*FUZZ+n]   (j=0..4)
// Spart[by][5+m][n]   = sum_{kk/3==m} row j=5;  [8+m]: kk%3==m, j=6
// Grid (3, 243), block 192 (3 waves). 2187 waves total, ~8.5/CU.
// ---------------------------------------------------------------------------
__global__ __launch_bounds__(192) void k_reduce_wei(const float* __restrict__ wei,
                                                    float* __restrict__ Spart) {
    int n4 = blockIdx.x * 192 + threadIdx.x;
    if (n4 > NF4) return;
    int by = blockIdx.y;
    const float* base = wei + (size_t)(by * 9) * 7 * FUZZ;
    float* outp = Spart + (size_t)by * PROWS * PSTR;

    if (n4 < NF4) {                       // vector path (63/64 lanes everywhere)
        float4 acc[PROWS];
#pragma unroll
        for (int r = 0; r < PROWS; ++r) acc[r] = make_float4(0.f, 0.f, 0.f, 0.f);
#pragma unroll
        for (int kk = 0; kk < 9; ++kk) {
            const float* rp = base + (size_t)kk * 7 * FUZZ + 4 * n4;
            float4 v0 = *(const float4*)(rp);
            float4 v1 = *(const float4*)(rp + (size_t)1 * FUZZ);
            float4 v2 = *(const float4*)(rp + (size_t)2 * FUZZ);
            float4 v3 = *(const float4*)(rp + (size_t)3 * FUZZ);
            float4 v4 = *(const float4*)(rp + (size_t)4 * FUZZ);
            float4 v5 = *(const float4*)(rp + (size_t)5 * FUZZ);
            float4 v6 = *(const float4*)(rp + (size_t)6 * FUZZ);
            f4add(acc[0], v0);
            f4add(acc[1], v1);
            f4add(acc[2], v2);
            f4add(acc[3], v3);
            f4add(acc[4], v4);
            f4add(acc[5 + kk / 3], v5);   // compile-time index
            f4add(acc[8 + kk % 3], v6);   // compile-time index
        }
#pragma unroll
        for (int r = 0; r < PROWS; ++r)
            *(float4*)(outp + (size_t)r * PSTR + 4 * n4) = acc[r];
    } else {                              // tail lane: columns 2184..2186
        float acc[PROWS][3];
#pragma unroll
        for (int r = 0; r < PROWS; ++r)
            for (int c = 0; c < 3; ++c) acc[r][c] = 0.f;
#pragma unroll
        for (int kk = 0; kk < 9; ++kk) {
            const float* rp = base + (size_t)kk * 7 * FUZZ + 2184;
#pragma unroll
            for (int j = 0; j < 7; ++j) {
                int row = (j < 5) ? j : ((j == 5) ? 5 + kk / 3 : 8 + kk % 3);
#pragma unroll
                for (int c = 0; c < 3; ++c)
                    acc[row][c] += rp[(size_t)j * FUZZ + c];
            }
        }
#pragma unroll
        for (int r = 0; r < PROWS; ++r)
            for (int c = 0; c < 3; ++c)
                outp[(size_t)r * PSTR + 2184 + c] = acc[r][c];
    }
}

// ---------------------------------------------------------------------------
// Kernel 2: recombine Spart into S[21][SSTR].
// t=j*3+m. j<5: sum Spart[by][j] over the 81 by with digit_j(by)==m
//          j=5: sum Spart[by][5+m] over all 243 by;  j=6: row 8+m.
// digit_j(by) = (by / place[j]) % 3, place = {81,27,9,3,1}.
// Grid (3, 21), block 192, float4.
// ---------------------------------------------------------------------------
__global__ __launch_bounds__(192) void k_reduce2(const float* __restrict__ Spart,
                                                 float* __restrict__ S) {
    int n4 = blockIdx.x * 192 + threadIdx.x;
    if (n4 > NF4) return;
    int t = blockIdx.y;
    int j = t / 3, m = t % 3;

    if (n4 < NF4) {
        float4 s = make_float4(0.f, 0.f, 0.f, 0.f);
        if (j < 5) {
            const int place[5] = {81, 27, 9, 3, 1};
            int ops[4];
            int o = 0;
            for (int q = 0; q < 5; ++q)
                if (q != j) ops[o++] = place[q];
            int byb = m * place[j];
            for (int c = 0; c < 81; ++c) {
                int by = byb + (c / 27) * ops[0] + ((c / 9) % 3) * ops[1]
                             + ((c / 3) % 3) * ops[2] + (c % 3) * ops[3];
                f4add(s, *(const float4*)(Spart + ((size_t)by * PROWS + j) * PSTR + 4 * n4));
            }
        } else {
            int row = (j == 5) ? 5 + m : 8 + m;
            for (int by = 0; by < NCH; ++by)
                f4add(s, *(const float4*)(Spart + ((size_t)by * PROWS + row) * PSTR + 4 * n4));
        }
        *(float4*)(S + (size_t)t * SSTR + 4 * n4) = s;
    } else {
        float s0 = 0.f, s1 = 0.f, s2 = 0.f;
        if (j < 5) {
            const int place[5] = {81, 27, 9, 3, 1};
            int ops[4];
            int o = 0;
            for (int q = 0; q < 5; ++q)
                if (q != j) ops[o++] = place[q];
            int byb = m * place[j];
            for (int c = 0; c < 81; ++c) {
                int by = byb + (c / 27) * ops[0] + ((c / 9) % 3) * ops[1]
                             + ((c / 3) % 3) * ops[2] + (c % 3) * ops[3];
                const float* p = Spart + ((size_t)by * PROWS + j) * PSTR + 2184;
                s0 += p[0]; s1 += p[1]; s2 += p[2];
            }
        } else {
            int row = (j == 5) ? 5 + m : 8 + m;
            for (int by = 0; by < NCH; ++by) {
                const float* p = Spart + ((size_t)by * PROWS + row) * PSTR + 2184;
                s0 += p[0]; s1 += p[1]; s2 += p[2];
            }
        }
        S[(size_t)t * SSTR + 2184] = s0;
        S[(size_t)t * SSTR + 2185] = s1;
        S[(size_t)t * SSTR + 2186] = s2;
    }
}

__device__ __forceinline__ float wave_sum(float v) {
#pragma unroll
    for (int off = 32; off > 0; off >>= 1) v += __shfl_down(v, off, 64);
    return v;
}

// ---------------------------------------------------------------------------
// Kernel 3: SW1[t][i] = sum_n S[t,n]*W1[i,n];  ws1[i] = sum_n W1[i,n]
// One 256-thread block per i (4 waves split the n-range, LDS combine).
// ---------------------------------------------------------------------------
__global__ __launch_bounds__(256) void k_sw1(const float* __restrict__ S,
                                             const float* __restrict__ W1,
                                             float* __restrict__ SW1,
                                             float* __restrict__ ws1) {
    int i = blockIdx.x;
    int tid = threadIdx.x;
    float acc[21];
    float aw = 0.f;
#pragma unroll
    for (int t = 0; t < 21; ++t) acc[t] = 0.f;
    for (int n = tid; n < FUZZ; n += 256) {
        float w1 = W1[(size_t)i * FUZZ + n];
        aw += w1;
#pragma unroll
        for (int t = 0; t < 21; ++t) acc[t] += S[t * SSTR + n] * w1;
    }
#pragma unroll
    for (int t = 0; t < 21; ++t) acc[t] = wave_sum(acc[t]);
    aw = wave_sum(aw);
    __shared__ float red[4][22];
    int w = tid >> 6, lane = tid & 63;
    if (lane == 0) {
#pragma unroll
        for (int t = 0; t < 21; ++t) red[w][t] = acc[t];
        red[w][21] = aw;
    }
    __syncthreads();
    if (tid < 22) {
        float v = red[0][tid] + red[1][tid] + red[2][tid] + red[3][tid];
        if (tid < 21) SW1[tid * MID + i] = v;
        else          ws1[i] = v;
    }
}

// ---------------------------------------------------------------------------
// Kernel 4: G[t][n] = sum_i SW1[t,i]*W2[n,i];  q[n] = sum_i ws1[i]*W2[n,i];
//           p[n] = sum_i b1[i]*W2[n,i].  One wave per n (2187 blocks).
// ---------------------------------------------------------------------------
__global__ __launch_bounds__(64) void k_g(const float* __restrict__ SW1,
                                          const float* __restrict__ ws1,
                                          const float* __restrict__ b1,
                                          const float* __restrict__ W2,
                                          float* __restrict__ G,
                                          float* __restrict__ q,
                                          float* __restrict__ p) {
    int n = blockIdx.x;
    int lane = threadIdx.x;
    float acc[21];
    float aq = 0.f, ap = 0.f;
#pragma unroll
    for (int t = 0; t < 21; ++t) acc[t] = 0.f;
    for (int i = lane; i < MID; i += 64) {
        float w2 = W2[(size_t)n * MID + i];
        aq += ws1[i] * w2;
        ap += b1[i] * w2;
#pragma unroll
        for (int t = 0; t < 21; ++t) acc[t] += SW1[t * MID + i] * w2;
    }
#pragma unroll
    for (int t = 0; t < 21; ++t) acc[t] = wave_sum(acc[t]);
    aq = wave_sum(aq);
    ap = wave_sum(ap);
    if (lane == 0) {
#pragma unroll
        for (int t = 0; t < 21; ++t) G[t * SSTR + n] = acc[t];
        q[n] = aq;
        p[n] = ap;
    }
}

// ---------------------------------------------------------------------------
// Kernel 5: H[t][c] = sum_n (S+G)[t,n]*W3[c,n]
//           v[c] = sum_n (1+q[n])*W3[c,n]
//           w[c] = sum_n (p[n]+b2[n])*W3[c,n] + b3[c]
//           T[t] = sum_n S[t,n]                      (block 10)
// 1024-thread blocks (16 waves, LDS combine), grid 11.
// ---------------------------------------------------------------------------
__global__ __launch_bounds__(1024) void k_h(const float* __restrict__ S,
                                            const float* __restrict__ G,
                                            const float* __restrict__ q,
                                            const float* __restrict__ p,
                                            const float* __restrict__ b2,
                                            const float* __restrict__ b3,
                                            const float* __restrict__ W3,
                                            float* __restrict__ H,
                                            float* __restrict__ v,
                                            float* __restrict__ w,
                                            float* __restrict__ T) {
    int c = blockIdx.x;
    int tid = threadIdx.x;
    int wv = tid >> 6, lane = tid & 63;
    __shared__ float red[16][24];
    float acc[21];
#pragma unroll
    for (int t = 0; t < 21; ++t) acc[t] = 0.f;
    if (c < NCLS) {
        float av = 0.f, aw = 0.f;
        for (int n = tid; n < FUZZ; n += 1024) {
            float w3 = W3[(size_t)c * FUZZ + n];
            av += (1.0f + q[n]) * w3;
            aw += (p[n] + b2[n]) * w3;
#pragma unroll
            for (int t = 0; t < 21; ++t)
                acc[t] += (S[t * SSTR + n] + G[t * SSTR + n]) * w3;
        }
#pragma unroll
        for (int t = 0; t < 21; ++t) acc[t] = wave_sum(acc[t]);
        av = wave_sum(av);
        aw = wave_sum(aw);
        if (lane == 0) {
#pragma unroll
            for (int t = 0; t < 21; ++t) red[wv][t] = acc[t];
            red[wv][21] = av;
            red[wv][22] = aw;
        }
        __syncthreads();
        if (tid < 23) {
            float s = 0.f;
#pragma unroll
            for (int k = 0; k < 16; ++k) s += red[k][tid];
            if (tid < 21)       H[tid * NCLS + c] = s;
            else if (tid == 21) v[c] = s;
            else                w[c] = s + b3[c];
        }
    } else {
        for (int n = tid; n < FUZZ; n += 1024) {
#pragma unroll
            for (int t = 0; t < 21; ++t) acc[t] += S[t * SSTR + n];
        }
#pragma unroll
        for (int t = 0; t < 21; ++t) acc[t] = wave_sum(acc[t]);
        if (lane == 0) {
#pragma unroll
            for (int t = 0; t < 21; ++t) red[wv][t] = acc[t];
        }
        __syncthreads();
        if (tid < 21) {
            float s = 0.f;
#pragma unroll
            for (int k = 0; k < 16; ++k) s += red[k][tid];
            T[tid] = s;
        }
    }
}

// ---------------------------------------------------------------------------
// Kernel 6: per-batch epilogue.
// ---------------------------------------------------------------------------
__global__ __launch_bounds__(256) void k_out(const float* __restrict__ x,
                                             const float* __restrict__ cc,
                                             const float* __restrict__ bbv,
                                             const float* __restrict__ bais,
                                             const float* __restrict__ T,
                                             const float* __restrict__ H,
                                             const float* __restrict__ v,
                                             const float* __restrict__ w,
                                             float* __restrict__ out) {
    int b = blockIdx.x * 256 + threadIdx.x;
    if (b >= BATCH) return;
    float xv[NFEAT];
#pragma unroll
    for (int j = 0; j < NFEAT; ++j) xv[j] = x[b * NFEAT + j];
    float u[21];
#pragma unroll
    for (int j = 0; j < NFEAT; ++j) {
#pragma unroll
        for (int m = 0; m < 3; ++m) {
            float d = xv[j] - cc[j * 3 + m];
            float bv = bbv[j * 3 + m];
            u[j * 3 + m] = expf(-(d * d) / (bv * bv));
        }
    }
    float ba = bais[0];
    float r = 2187.0f * ba;
#pragma unroll
    for (int t = 0; t < 21; ++t) r += u[t] * T[t];
    float inv = 1.0f / r;
#pragma unroll
    for (int c = 0; c < NCLS; ++c) {
        float s = 0.f;
#pragma unroll
        for (int t = 0; t < 21; ++t) s += u[t] * H[t * NCLS + c];
        float h = (s + ba * v[c]) * inv + w[c];
        out[b * NCLS + c] = (h >= 0.f) ? h : 0.2f * h;
    }
}

extern "C" void kernel_launch(void* const* d_in, const int* in_sizes, int n_in,
                              void* d_out, int out_size, void* d_ws, size_t ws_size,
                              hipStream_t stream) {
    const float* x    = (const float*)d_in[0];
    const float* c    = (const float*)d_in[1];
    const float* bbv  = (const float*)d_in[2];
    const float* wei  = (const float*)d_in[3];
    const float* bais = (const float*)d_in[4];
    const float* W1   = (const float*)d_in[5];
    const float* b1   = (const float*)d_in[6];
    const float* W2   = (const float*)d_in[7];
    const float* b2   = (const float*)d_in[8];
    const float* W3   = (const float*)d_in[9];
    const float* b3   = (const float*)d_in[10];

    float* ws    = (float*)d_ws;
    float* Spart = ws;                                   // 243*11*2188 = 5,848,524
    float* S     = Spart + 5848528;                      // 21*SSTR (16B-aligned)
    float* G     = S + 21 * SSTR;                        // 21*SSTR
    float* SW1   = G + 21 * SSTR;                        // 21*512
    float* ws1   = SW1 + 21 * MID;                       // 512
    float* q     = ws1 + MID;                            // SSTR
    float* p     = q + SSTR;                             // SSTR
    float* T     = p + SSTR;                             // 32
    float* H     = T + 32;                               // 224 (21*10 used)
    float* v     = H + 224;                              // 16
    float* w     = v + 16;                               // 16

    k_reduce_wei<<<dim3(3, NCH), 192, 0, stream>>>(wei, Spart);
    k_reduce2<<<dim3(3, 21), 192, 0, stream>>>(Spart, S);
    k_sw1<<<MID, 256, 0, stream>>>(S, W1, SW1, ws1);
    k_g<<<FUZZ, 64, 0, stream>>>(SW1, ws1, b1, W2, G, q, p);
    k_h<<<NCLS + 1, 1024, 0, stream>>>(S, G, q, p, b2, b3, W3, H, v, w, T);
    k_out<<<(BATCH + 255) / 256, 256, 0, stream>>>(x, c, bbv, bais, T, H, v, w,
                                                   (float*)d_out);
}